// Round 12
// baseline (1900.902 us; speedup 1.0000x reference)
//
#include <hip/hip_runtime.h>

// AdEx Euler integration, fp32 port of the jax/numpy reference.
// T=40000 sequential steps; N=1024 neurons -> 16 producer waves on 16 CUs.
//
// MODEL (R1-R24): lone in-order producer wave; wall = dependency-chained
// issue. Measured ~70 cyc/step: 8 VALU x5.6 + exp ~11 (1/4-rate trans) +
// DS ~2 (shadowed, R24) + VMEM 0.5x13 + ~2 overhead. Proven-out: C-level
// reg prefetch arrays get SUNK (R15); AD via LDS serializes on lgkmcnt
// (R16); per-step uniform branch = +18cyc/step hazard (R18, banned);
// pk_add epilogue fusion = wash (R22); VMEM-in-exp-shadow = 0, and
// vmcnt(0)-per-buffer drain costs +2cyc/step (R23).
// Ladder: R17 1354; R19 1340; R20 1298; R21 1186; R24 1164.
// R25 submission hit "MI355X container failed twice" (infra; no compile
// log, no measurement) -> RESUBMIT unchanged. Audit: deadlock-free (R24
// flag protocol), OOB-safe (tail reads < T*8+256 workspace), scalar-K$
// coherent across dispatch boundary (VMEM path proved it R15-R24), SGPR
// in-loop live set ~80 < 102.
//
// R25: AD moved to the SCALAR pipe. AD is LANE-UNIFORM (depends only on
// timestep) -- the VMEM port was paying broadcast tax (~13cyc/issue,
// R21-measured). Now: s_load_dwordx4 into SGPR quads; v_pk_fma src2 reads
// the {Ar2,delta} SGPR pair DIRECTLY (VOP3P scalar source; 1-SGPR rule
// OK: cAG/VW are VGPRs, vcc doesn't count). Sub-pair extracts from
// s-quads are even-aligned subregs -> zero-mov expected (R21 mechanism).
// SGPR budget forces half-buffer sets: 2 x 8 quads (32 SGPR each),
// prefetch distance = 16 steps (~1100cyc >> SMEM latency), lgkmcnt(0) per
// half ~free (youngest ds_write ~70-140cyc, youngest SMEM ~1100cyc;
// only-wait-on-0 makes SMEM out-of-order safe). Everything else exactly
// R24 (ring, shadowed ds_write2st64, flags, math).
// Ledger: -16 VMEM x13 / 32 steps, +16 SMEM +2 waits at SALU cadence
// -> net ~ -3 cyc/step. Predict kernel ~1110-1140us; absmax EXACTLY
// 4.882812e-04; conflicts 0; VGPR drops to ~70-90 (A4/B4 die), SGPR up.
// If >=1155: levers spent -> declare structural ceiling next round.

typedef float v2f __attribute__((ext_vector_type(2)));
typedef float v4f __attribute__((ext_vector_type(4)));

// ---------------------------------------------------------------------------
// Prep: AD[k] = {Ar2_k, delta} for k in [0, T+32). Bit-identical constant
// folding to the producer's original in-loop computation (same f64
// expressions, rounded once to f32; same fmaf on the same I value).
// ---------------------------------------------------------------------------
__global__ void __launch_bounds__(256) adex_prep_kernel(
    const float* __restrict__ I_ext,
    const float* __restrict__ p_V_rest,
    const float* __restrict__ p_R,
    const float* __restrict__ p_tau,
    const float* __restrict__ p_tau_w,
    const float* __restrict__ p_a,
    float2* __restrict__ AD, int T)
{
#pragma clang fp contract(off)
    int k = blockIdx.x * 256 + threadIdx.x;
    if (k >= T + 32) return;

    const float V_rest = *p_V_rest;
    const float R      = *p_R;
    const float tau    = *p_tau;
    const float tau_w  = *p_tau_w;
    const float a      = *p_a;
    const float dt     = 5e-5f;

    const double dcv = (double)dt / (double)tau;
    const double dcw = (double)dt / (double)tau_w;

    const float cRI   = (float)(dcv * (double)R);
    const float cVr2  = (float)(dcv * (double)V_rest);
    const float delta = (float)(-(double)a * dcw * (double)V_rest);

    int ki = (k <= T + 4) ? k : (T + 4);      // tail entries never consumed
    AD[k] = make_float2(fmaf(cRI, I_ext[ki], cVr2), delta);
}

// ---------------------------------------------------------------------------
// Main producer/consumer kernel.
// ---------------------------------------------------------------------------
__global__ void __launch_bounds__(128, 1) adex_pc_kernel(
    const float* __restrict__ V0,
    const float* __restrict__ w0,
    const float* __restrict__ p_V_reset,
    const float* __restrict__ p_V_T,
    const float* __restrict__ p_V_thres,
    const float* __restrict__ p_delta_T,
    const float* __restrict__ p_R,
    const float* __restrict__ p_tau,
    const float* __restrict__ p_tau_w,
    const float* __restrict__ p_a,
    const float* __restrict__ p_b,
    const float* __restrict__ ADf,       // workspace: {Ar2,delta} pairs
    float* __restrict__ out,
    int T, int N)
{
#pragma clang fp contract(off)
    // Ring of 4 buffers x 32 steps x 64 lanes x float2 = 64 KiB.
    // [buf][step][lane]: lane stride 8B (conflict-free, measured 0);
    // step stride 512B = the ds_*st64 b64 unit.
    __shared__ v2f stage[4][32][64];
    __shared__ int flags[2];             // [0]=produced bufs, [1]=consumed

    const int tid   = threadIdx.x;
    const int l     = tid & 63;
    const int wave  = tid >> 6;
    const int nbase = blockIdx.x * 64;   // N % 64 == 0

    volatile int* vflags = (volatile int*)flags;
    if (tid < 2) flags[tid] = 0;
    __syncthreads();                     // once, at kernel start only

    const int NB = T >> 5;               // 32-step buffers (T % 64 == 0 -> NB even)

    if (wave == 0) {
        // ---------------- producer: the serial recurrence ----------------
        __builtin_amdgcn_s_setprio(3);   // favor the serial-chain wave

        const float V_reset = *p_V_reset;
        const float V_T     = *p_V_T;
        const float V_thres = *p_V_thres;
        const float delta_T = *p_delta_T;
        const float R       = *p_R;
        const float tau     = *p_tau;
        const float tau_w   = *p_tau_w;
        const float a       = *p_a;
        const float b       = *p_b;
        const float dt      = 5e-5f;

        // Constants folded in f64, rounded once to f32 (bit-neutral class).
        const double dT  = (double)delta_T;
        const double dcv = (double)dt / (double)tau;
        const double dcw = (double)dt / (double)tau_w;
        const double l2e = 1.4426950408889634;

        const float c_exp = (float)(l2e / dT);
        const float c2    = (float)(log2(dT * dcv) - (double)V_T * (l2e / dT));
        const float alpha = (float)(1.0 - dcv);
        const float ncRv  = (float)(-dcv * (double)R);
        const float beta  = (float)(1.0 - dcw);
        const float gamma = (float)((double)a * dcw);

        // Packed coefficient pairs for v_pk_fma_f32.
        v2f cAG; cAG.x = alpha; cAG.y = gamma;
        v2f cNB; cNB.x = ncRv;  cNB.y = beta;

        // Ping-pong packed state {V, w}. VWa = state entering the step pair.
        v2f VWa, VWb;
        VWa.x = V0[nbase + l];
        VWa.y = w0[nbase + l];

        // AD half-buffer SGPR sets: 8 quads = 32 SGPRs each (16 steps).
        // Defined only by volatile s_load asm -> unsinkable, resident.
        v4f SA[8], SB[8];
        unsigned long long abase = (unsigned long long)ADf;  // +256 B/buffer

        // Issue one half-buffer (8 step-pairs) of {Ar2,delta} via SMEM.
#define SLOAD_HALF(SET, BOFF)                                             \
        {                                                                 \
            _Pragma("unroll")                                             \
            for (int j = 0; j < 8; ++j)                                   \
                asm volatile("s_load_dwordx4 %0, %1, %2"                  \
                             : "=s"(SET[j])                               \
                             : "s"(abase), "n"((BOFF) + j * 16));         \
        }

        // One step S -> D with an optional FILLER placed between exp and
        // pk1 (the exp latency shadow, R24-proven). All fp ops value-
        // identical to the verified R14/R21 math:
        //   P1.lo = fma(alpha,S.V,Ar2)   P1.hi = fma(gamma,S.V,delta)
        //   D.lo  = fma(ncRv,S.w,P1.lo)  D.hi  = fma(beta,S.w,P1.hi)
        //   D.V  += 2^fma(S.V,c_exp,c2); unconditional spike selects
        // (NO per-step branch -- R18 lesson). ADW is an SGPR pair (src2).
#define STEPF(S, D, ADW, ...)                                             \
        {                                                                 \
            float u  = fmaf((S).x, c_exp, c2);                            \
            bool  sp = (S).x > V_thres;                                   \
            float ex;                                                     \
            asm("v_exp_f32 %0, %1" : "=v"(ex) : "v"(u));                  \
            __VA_ARGS__;                                                  \
            v2f P1;                                                       \
            asm("v_pk_fma_f32 %0, %1, %2, %3 op_sel:[0,0,0] op_sel_hi:[1,0,1]" \
                : "=v"(P1) : "v"(cAG), "v"(S), "s"(ADW));                 \
            asm("v_pk_fma_f32 %0, %1, %2, %3 op_sel:[0,1,0] op_sel_hi:[1,1,1]" \
                : "=v"(D) : "v"(cNB), "v"(S), "v"(P1));                   \
            (D).x += ex;                                                  \
            float wns = (D).y + b;                                        \
            (D).x = sp ? V_reset : (D).x;                                 \
            (D).y = sp ? wns : (D).y;                                     \
        }

        // One pair (steps 2s, 2s+1) from s-quad Q; ds_write2st64 in step
        // B's exp shadow (R24-proven placement, bit-exact).
#define PAIR(Q, s)                                                        \
        {                                                                 \
            v4f q = (Q);                                                  \
            v2f ad0 = __builtin_shufflevector(q, q, 0, 1);                \
            v2f ad1 = __builtin_shufflevector(q, q, 2, 3);                \
            STEPF(VWa, VWb, ad0, );                                       \
            STEPF(VWb, VWa, ad1,                                          \
                asm volatile("ds_write2st64_b64 %0, %1, %2 offset0:%3 offset1:%4" \
                             :: "v"(lds_a), "v"(VWa), "v"(VWb),           \
                                "n"(2 * (s)), "n"(2 * (s) + 1)));         \
        }

        // One 32-step buffer, two halves. Per half: lgkmcnt(0) makes the
        // half's SGPR set ready (its s_loads issued 16 steps ~1100cyc ago;
        // youngest ds_write ~70-140cyc -> both ~retired, near-free; only-0
        // waits keep SMEM out-of-order safe), then issue the NEXT half's
        // s_loads, then 8 step-pairs. sched_barrier per rule #18. NO LGKM0
        // before the flag write (DS pipe in-order per wave, R19-proven).
#define PRODUCE()                                                         \
        {                                                                 \
            unsigned lds_a = (unsigned)(unsigned long long)               \
                (__attribute__((address_space(3))) void*)&stage[pi & 3][0][l]; \
            asm volatile("s_waitcnt lgkmcnt(0)");                         \
            __builtin_amdgcn_sched_barrier(0);                            \
            SLOAD_HALF(SB, 128);       /* this buffer, steps 16-31 */     \
            PAIR(SA[0], 0)  PAIR(SA[1], 1)  PAIR(SA[2], 2)  PAIR(SA[3], 3) \
            PAIR(SA[4], 4)  PAIR(SA[5], 5)  PAIR(SA[6], 6)  PAIR(SA[7], 7) \
            asm volatile("s_waitcnt lgkmcnt(0)");                         \
            __builtin_amdgcn_sched_barrier(0);                            \
            SLOAD_HALF(SA, 256);       /* next buffer, steps 0-15 */      \
            PAIR(SB[0], 8)  PAIR(SB[1], 9)  PAIR(SB[2], 10) PAIR(SB[3], 11) \
            PAIR(SB[4], 12) PAIR(SB[5], 13) PAIR(SB[6], 14) PAIR(SB[7], 15) \
            asm volatile("" ::: "memory");                                \
            ++pi;                                                         \
            vflags[0] = pi;                                               \
            abase += 256;                                                 \
        }

        // Prologue: buffer 0 first half into SA (first lgkmcnt(0) eats one
        // full SMEM latency once -- negligible).
        SLOAD_HALF(SA, 0);

        int pi = 0;
        while (pi < NB) {
            // Back-pressure (ring 4 deep): producing pi and pi+1 needs
            // consumed >= pi-2. Single flag read per 2 buffers; its
            // compiler lgkm-wait drains only retired ops (~free).
            int fc = vflags[1];
            if (fc < pi - 2) {
                while (vflags[1] < pi - 2) __builtin_amdgcn_s_sleep(2);
            }
            asm volatile("" ::: "memory");

            PRODUCE();     // buffer pi
            PRODUCE();     // buffer pi+1 (its tail SLOAD reads the
                           // (T+32)-entry AD tail; never consumed)
        }
#undef PRODUCE
#undef PAIR
#undef STEPF
#undef SLOAD_HALF
    } else {
        // ---------------- consumer: drain LDS -> global ----------------
        float* __restrict__ outw = out + (size_t)T * N;
        unsigned idx = (unsigned)(nbase + l);      // += N per step

        for (int ci = 0; ci < NB; ++ci) {
            while (vflags[0] < ci + 1) __builtin_amdgcn_s_sleep(2);
            asm volatile("" ::: "memory");
            const v2f* cb = &stage[ci & 3][0][l];
#pragma unroll
            for (int s = 0; s < 32; ++s) {
                v2f q = cb[s * 64];
                out[idx]  = q.x;
                outw[idx] = q.y;
                idx += (unsigned)N;
            }
            // LDS reads retired (store data deps forced waits); slot free.
            asm volatile("" ::: "memory");
            vflags[1] = ci + 1;
        }
    }
}

// Fallback: R11-style single-wave kernel for shapes that don't meet the
// producer/consumer preconditions (N%64, T%64, workspace size).
__global__ void __launch_bounds__(64, 1) adex_fallback_kernel(
    const float* __restrict__ I_ext,
    const float* __restrict__ V0,
    const float* __restrict__ w0,
    const float* __restrict__ p_V_rest,
    const float* __restrict__ p_V_reset,
    const float* __restrict__ p_V_T,
    const float* __restrict__ p_V_thres,
    const float* __restrict__ p_delta_T,
    const float* __restrict__ p_R,
    const float* __restrict__ p_tau,
    const float* __restrict__ p_tau_w,
    const float* __restrict__ p_a,
    const float* __restrict__ p_b,
    float* __restrict__ out,
    int T, int N)
{
#pragma clang fp contract(off)
    const int l     = threadIdx.x;
    const int nbase = blockIdx.x * 64;
    int n = nbase + l;
    if (n >= N) n = N - 1;

    const float V_rest  = *p_V_rest;
    const float V_reset = *p_V_reset;
    const float V_T     = *p_V_T;
    const float V_thres = *p_V_thres;
    const float delta_T = *p_delta_T;
    const float R       = *p_R;
    const float tau     = *p_tau;
    const float tau_w   = *p_tau_w;
    const float a       = *p_a;
    const float b       = *p_b;
    const float dt      = 5e-5f;

    const double dT  = (double)delta_T;
    const double dcv = (double)dt / (double)tau;
    const double dcw = (double)dt / (double)tau_w;
    const double l2e = 1.4426950408889634;

    const float c_exp = (float)(l2e / dT);
    const float c2    = (float)(log2(dT * dcv) - (double)V_T * (l2e / dT));
    const float alpha = (float)(1.0 - dcv);
    const float ncRv  = (float)(-dcv * (double)R);
    const float beta  = (float)(1.0 - dcw);
    const float gamma = (float)((double)a * dcw);
    const float delta = (float)(-(double)a * dcw * (double)V_rest);
    const float cRI   = (float)(dcv * (double)R);
    const float cVr2  = (float)(dcv * (double)V_rest);

    float V = V0[n];
    float w = w0[n];

    float* outVb = out + nbase;
    float* outWb = out + (size_t)T * N + nbase;

#define ADEX_STEP(Ar2_k)                                            \
    {                                                               \
        outVb[l] = V;                                               \
        outWb[l] = w;                                               \
        outVb += N;                                                 \
        outWb += N;                                                 \
        float u3 = fmaf(V, c_exp, c2);                              \
        float ex3;                                                  \
        asm("v_exp_f32 %0, %1" : "=v"(ex3) : "v"(u3));              \
        float m1  = fmaf(alpha, V, (Ar2_k));                        \
        float m2  = fmaf(ncRv, w, m1);                              \
        float Vn  = m2 + ex3;                                       \
        float t2  = fmaf(gamma, V, delta);                          \
        float wn  = fmaf(beta, w, t2);                              \
        bool  spike = V > V_thres;                                  \
        float wns = wn + b;                                         \
        Vn = spike ? V_reset : Vn;                                  \
        wn = spike ? wns : wn;                                      \
        V = Vn;                                                     \
        w = wn;                                                     \
    }

    float A[16], B[16];
#pragma unroll
    for (int j = 0; j < 16; ++j) A[j] = fmaf(cRI, I_ext[j], cVr2);

    for (int kb = 0; kb < T; kb += 32) {
#pragma unroll
        for (int j = 0; j < 16; ++j)
            B[j] = fmaf(cRI, I_ext[kb + 16 + j], cVr2);
#pragma unroll
        for (int j = 0; j < 16; ++j) ADEX_STEP(A[j]);
        {
            int pb = kb + 32;
            if (pb > T - 11) pb = T - 11;
#pragma unroll
            for (int j = 0; j < 16; ++j)
                A[j] = fmaf(cRI, I_ext[pb + j], cVr2);
        }
#pragma unroll
        for (int j = 0; j < 16; ++j) ADEX_STEP(B[j]);
    }
#undef ADEX_STEP
}

extern "C" void kernel_launch(void* const* d_in, const int* in_sizes, int n_in,
                              void* d_out, int out_size, void* d_ws, size_t ws_size,
                              hipStream_t stream) {
    const float* I_ext = (const float*)d_in[0];
    const float* V0    = (const float*)d_in[1];
    const float* w0    = (const float*)d_in[2];

    const int N = in_sizes[1];          // 1024 (multiple of 64)
    const int T = out_size / (2 * N);   // 40000 (multiple of 64)

    const size_t ws_need = (size_t)(T + 32) * sizeof(float2);

    if ((N % 64 == 0) && (T % 64 == 0) && d_ws != nullptr && ws_size >= ws_need) {
        adex_prep_kernel<<<(T + 32 + 255) / 256, 256, 0, stream>>>(
            I_ext,
            (const float*)d_in[3],      // V_rest
            (const float*)d_in[8],      // R
            (const float*)d_in[9],      // tau
            (const float*)d_in[10],     // tau_w
            (const float*)d_in[11],     // a
            (float2*)d_ws, T);
        adex_pc_kernel<<<N / 64, 128, 0, stream>>>(
            V0, w0,
            (const float*)d_in[4],      // V_reset
            (const float*)d_in[5],      // V_T
            (const float*)d_in[6],      // V_thres
            (const float*)d_in[7],      // delta_T
            (const float*)d_in[8],      // R
            (const float*)d_in[9],      // tau
            (const float*)d_in[10],     // tau_w
            (const float*)d_in[11],     // a
            (const float*)d_in[12],     // b
            (const float*)d_ws,
            (float*)d_out, T, N);
    } else {
        adex_fallback_kernel<<<(N + 63) / 64, 64, 0, stream>>>(
            I_ext, V0, w0,
            (const float*)d_in[3], (const float*)d_in[4], (const float*)d_in[5],
            (const float*)d_in[6], (const float*)d_in[7], (const float*)d_in[8],
            (const float*)d_in[9], (const float*)d_in[10], (const float*)d_in[11],
            (const float*)d_in[12], (float*)d_out, T, N);
    }
}

// Round 13
// 1438.079 us; speedup vs baseline: 1.3218x; 1.3218x over previous
//
#include <hip/hip_runtime.h>

// AdEx Euler integration, fp32 port of the jax/numpy reference.
// T=40000 sequential steps; N=1024 neurons -> 16 producer waves on 16 CUs.
//
// FINAL (R26 = revert to R24, best verified: 1164us kernel).
//
// MODEL (R1-R25): lone in-order producer wave; wall = dependency-chained
// issue of the serial recurrence, ~70 cyc/step: 8 VALU x5.6 + exp ~11
// (1/4-rate trans) + DS ~2 (shadowed) + VMEM 0.5x13 + ~2 overhead.
// Measured 69.9 cyc/step -> within ~5% of the honest floor. No resource
// roofline applies (HBM 3.5%, VALUBusy 1.3%, conflicts 0).
//
// Proven-out (do NOT retry):
//   R15: C-level reg prefetch arrays get SUNK by compiler (wash).
//   R16: AD via LDS serializes on lgkmcnt + bank conflicts (+640us).
//   R18: per-step uniform branch = VALU->SGPR->SALU->branch hazard,
//        +18cyc/step even never-taken (banned).
//   R22: pk_add epilogue fusion = exact wash (insert-mov eats the slot).
//   R23: VMEM in exp shadow buys 0; vmcnt(0)-per-buffer drain +2cyc/step.
//   R25: AD via scalar pipe (s_load/sK$) REGRESSES +28cyc/step: sK$
//        streams 320KB with poor miss pipelining (FETCH doubled), and
//        VGPR stayed 132 (copies re-inserted). Lane-uniform != scalar-pipe
//        for STREAMING data; VMEM+L2 was already the right port.
//
// Winning ladder: R13 producer/consumer split 1727; R14 write-pairing
// 1632; R17 UNSINKABLE volatile-asm load double-buffer 1354; R19 no-LGKM0
// + poll-hiding 1340; R20 ds_write2st64_b64 pair staging + setprio(3)
// 1298; R21 dwordx4 AD loads 1186; R24 ds_write in exp shadow 1164.
//
// Structural ceiling: 40000 serial steps x bit-exact 9-op DAG on an
// in-order wave. Fewer steps or a shorter chain changes rounding ->
// violates the absmax 4.882812e-04 contract. This is the floor.

typedef float v2f __attribute__((ext_vector_type(2)));
typedef float v4f __attribute__((ext_vector_type(4)));

// ---------------------------------------------------------------------------
// Prep: AD[k] = {Ar2_k, delta} for k in [0, T+32). Bit-identical constant
// folding to the producer's original in-loop computation (same f64
// expressions, rounded once to f32; same fmaf on the same I value).
// ---------------------------------------------------------------------------
__global__ void __launch_bounds__(256) adex_prep_kernel(
    const float* __restrict__ I_ext,
    const float* __restrict__ p_V_rest,
    const float* __restrict__ p_R,
    const float* __restrict__ p_tau,
    const float* __restrict__ p_tau_w,
    const float* __restrict__ p_a,
    float2* __restrict__ AD, int T)
{
#pragma clang fp contract(off)
    int k = blockIdx.x * 256 + threadIdx.x;
    if (k >= T + 32) return;

    const float V_rest = *p_V_rest;
    const float R      = *p_R;
    const float tau    = *p_tau;
    const float tau_w  = *p_tau_w;
    const float a      = *p_a;
    const float dt     = 5e-5f;

    const double dcv = (double)dt / (double)tau;
    const double dcw = (double)dt / (double)tau_w;

    const float cRI   = (float)(dcv * (double)R);
    const float cVr2  = (float)(dcv * (double)V_rest);
    const float delta = (float)(-(double)a * dcw * (double)V_rest);

    int ki = (k <= T + 4) ? k : (T + 4);      // tail entries never consumed
    AD[k] = make_float2(fmaf(cRI, I_ext[ki], cVr2), delta);
}

// ---------------------------------------------------------------------------
// Main producer/consumer kernel.
// ---------------------------------------------------------------------------
__global__ void __launch_bounds__(128, 1) adex_pc_kernel(
    const float* __restrict__ V0,
    const float* __restrict__ w0,
    const float* __restrict__ p_V_reset,
    const float* __restrict__ p_V_T,
    const float* __restrict__ p_V_thres,
    const float* __restrict__ p_delta_T,
    const float* __restrict__ p_R,
    const float* __restrict__ p_tau,
    const float* __restrict__ p_tau_w,
    const float* __restrict__ p_a,
    const float* __restrict__ p_b,
    const float* __restrict__ ADf,       // workspace: {Ar2,delta} pairs
    float* __restrict__ out,
    int T, int N)
{
#pragma clang fp contract(off)
    // Ring of 4 buffers x 32 steps x 64 lanes x float2 = 64 KiB.
    // [buf][step][lane]: lane stride 8B (conflict-free, measured 0);
    // step stride 512B = the ds_*st64 b64 unit.
    __shared__ v2f stage[4][32][64];
    __shared__ int flags[2];             // [0]=produced bufs, [1]=consumed

    const int tid   = threadIdx.x;
    const int l     = tid & 63;
    const int wave  = tid >> 6;
    const int nbase = blockIdx.x * 64;   // N % 64 == 0

    volatile int* vflags = (volatile int*)flags;
    if (tid < 2) flags[tid] = 0;
    __syncthreads();                     // once, at kernel start only

    const int NB = T >> 5;               // 32-step buffers (T % 64 == 0 -> NB even)

    if (wave == 0) {
        // ---------------- producer: the serial recurrence ----------------
        __builtin_amdgcn_s_setprio(3);   // favor the serial-chain wave

        const float V_reset = *p_V_reset;
        const float V_T     = *p_V_T;
        const float V_thres = *p_V_thres;
        const float delta_T = *p_delta_T;
        const float R       = *p_R;
        const float tau     = *p_tau;
        const float tau_w   = *p_tau_w;
        const float a       = *p_a;
        const float b       = *p_b;
        const float dt      = 5e-5f;

        // Constants folded in f64, rounded once to f32 (bit-neutral class).
        const double dT  = (double)delta_T;
        const double dcv = (double)dt / (double)tau;
        const double dcw = (double)dt / (double)tau_w;
        const double l2e = 1.4426950408889634;

        const float c_exp = (float)(l2e / dT);
        const float c2    = (float)(log2(dT * dcv) - (double)V_T * (l2e / dT));
        const float alpha = (float)(1.0 - dcv);
        const float ncRv  = (float)(-dcv * (double)R);
        const float beta  = (float)(1.0 - dcw);
        const float gamma = (float)((double)a * dcw);

        // Packed coefficient pairs for v_pk_fma_f32.
        v2f cAG; cAG.x = alpha; cAG.y = gamma;
        v2f cNB; cNB.x = ncRv;  cNB.y = beta;

        // Ping-pong packed state {V, w}. VWa = state entering the step pair.
        v2f VWa, VWb;
        VWa.x = V0[nbase + l];
        VWa.y = w0[nbase + l];

        // AD double-buffer register sets (16 quads = 64 VGPR each), defined
        // only by volatile asm loads -> unsinkable, guaranteed resident.
        v4f A4[16], B4[16];
        const unsigned long long adbase = (unsigned long long)ADf;

#define LDSET(ARR, VOFF)                                                  \
        {                                                                 \
            unsigned _vo = (VOFF);                                        \
            _Pragma("unroll")                                             \
            for (int j = 0; j < 16; ++j)                                  \
                asm volatile("global_load_dwordx4 %0, %1, %2 offset:%3"   \
                             : "=v"(ARR[j])                               \
                             : "v"(_vo), "s"(adbase), "n"(j * 16));       \
        }

        // One step S -> D with an optional FILLER placed between exp and
        // pk1 (the exp latency shadow). All fp ops value-identical to the
        // verified R14/R21 math:
        //   P1.lo = fma(alpha,S.V,Ar2)   P1.hi = fma(gamma,S.V,delta)
        //   D.lo  = fma(ncRv,S.w,P1.lo)  D.hi  = fma(beta,S.w,P1.hi)
        //   D.V  += 2^fma(S.V,c_exp,c2); unconditional spike selects
        // (NO per-step branch -- R18 lesson).
#define STEPF(S, D, ADW, ...)                                             \
        {                                                                 \
            float u  = fmaf((S).x, c_exp, c2);                            \
            bool  sp = (S).x > V_thres;                                   \
            float ex;                                                     \
            asm("v_exp_f32 %0, %1" : "=v"(ex) : "v"(u));                  \
            __VA_ARGS__;                                                  \
            v2f P1;                                                       \
            asm("v_pk_fma_f32 %0, %1, %2, %3 op_sel:[0,0,0] op_sel_hi:[1,0,1]" \
                : "=v"(P1) : "v"(cAG), "v"(S), "v"(ADW));                 \
            asm("v_pk_fma_f32 %0, %1, %2, %3 op_sel:[0,1,0] op_sel_hi:[1,1,1]" \
                : "=v"(D) : "v"(cNB), "v"(S), "v"(P1));                   \
            (D).x += ex;                                                  \
            float wns = (D).y + b;                                        \
            (D).x = sp ? V_reset : (D).x;                                 \
            (D).y = sp ? wns : (D).y;                                     \
        }

        // One 32-step buffer from register set ARR (R21 structure: burst
        // prefetch + vmcnt(16); the 16 newest loads = next buffer stay in
        // flight, ARR's older loads are drained -> resident).
        // ds_write2st64 issues inside step B's exp shadow (R24 win): it
        // reads VWa (pre-state 2s) and VWb (pre-state 2s+1) -- both final
        // there; step B's later redefinition of VWa is SSA-safe. NO LGKM0
        // before the flag write (DS pipe in-order per wave, R19-proven).
        // sched_barrier per rule #18.
#define PRODUCE(ARR)                                                      \
        {                                                                 \
            asm volatile("s_waitcnt vmcnt(16)");                          \
            __builtin_amdgcn_sched_barrier(0);                            \
            unsigned lds_a = (unsigned)(unsigned long long)               \
                (__attribute__((address_space(3))) void*)&stage[pi & 3][0][l]; \
            _Pragma("unroll")                                             \
            for (int s = 0; s < 16; ++s) {                                \
                v4f q = ARR[s];                                           \
                v2f ad0 = __builtin_shufflevector(q, q, 0, 1);            \
                v2f ad1 = __builtin_shufflevector(q, q, 2, 3);            \
                STEPF(VWa, VWb, ad0, );                                   \
                STEPF(VWb, VWa, ad1,                                      \
                    asm volatile("ds_write2st64_b64 %0, %1, %2 offset0:%3 offset1:%4" \
                                 :: "v"(lds_a), "v"(VWa), "v"(VWb),       \
                                    "n"(2 * s), "n"(2 * s + 1)));         \
            }                                                             \
            asm volatile("" ::: "memory");                                \
            ++pi;                                                         \
            vflags[0] = pi;                                               \
        }

        // Prologue: buffer 0 into set A.
        LDSET(A4, 0u);

        int pi = 0;
        unsigned voff = 0;
        while (pi < NB) {
            // Back-pressure (ring 4 deep): producing pi and pi+1 needs
            // consumed >= pi-2. Flag pre-read BEFORE the LDSET burst hides
            // the ~120cyc LDS latency; poll loop only if consumer behind.
            int fc = vflags[1];
            voff += 256;
            LDSET(B4, voff);       // buffer pi+1
            if (fc < pi - 2) {
                while (vflags[1] < pi - 2) __builtin_amdgcn_s_sleep(2);
            }
            asm volatile("" ::: "memory");

            PRODUCE(A4);

            voff += 256;
            LDSET(A4, voff);       // buffer pi+2 (last issue reads the
                                   // (T+32)-entry AD tail; never consumed)
            PRODUCE(B4);
        }
#undef PRODUCE
#undef STEPF
#undef LDSET
    } else {
        // ---------------- consumer: drain LDS -> global ----------------
        float* __restrict__ outw = out + (size_t)T * N;
        unsigned idx = (unsigned)(nbase + l);      // += N per step

        for (int ci = 0; ci < NB; ++ci) {
            while (vflags[0] < ci + 1) __builtin_amdgcn_s_sleep(2);
            asm volatile("" ::: "memory");
            const v2f* cb = &stage[ci & 3][0][l];
#pragma unroll
            for (int s = 0; s < 32; ++s) {
                v2f q = cb[s * 64];
                out[idx]  = q.x;
                outw[idx] = q.y;
                idx += (unsigned)N;
            }
            // LDS reads retired (store data deps forced waits); slot free.
            asm volatile("" ::: "memory");
            vflags[1] = ci + 1;
        }
    }
}

// Fallback: R11-style single-wave kernel for shapes that don't meet the
// producer/consumer preconditions (N%64, T%64, workspace size).
__global__ void __launch_bounds__(64, 1) adex_fallback_kernel(
    const float* __restrict__ I_ext,
    const float* __restrict__ V0,
    const float* __restrict__ w0,
    const float* __restrict__ p_V_rest,
    const float* __restrict__ p_V_reset,
    const float* __restrict__ p_V_T,
    const float* __restrict__ p_V_thres,
    const float* __restrict__ p_delta_T,
    const float* __restrict__ p_R,
    const float* __restrict__ p_tau,
    const float* __restrict__ p_tau_w,
    const float* __restrict__ p_a,
    const float* __restrict__ p_b,
    float* __restrict__ out,
    int T, int N)
{
#pragma clang fp contract(off)
    const int l     = threadIdx.x;
    const int nbase = blockIdx.x * 64;
    int n = nbase + l;
    if (n >= N) n = N - 1;

    const float V_rest  = *p_V_rest;
    const float V_reset = *p_V_reset;
    const float V_T     = *p_V_T;
    const float V_thres = *p_V_thres;
    const float delta_T = *p_delta_T;
    const float R       = *p_R;
    const float tau     = *p_tau;
    const float tau_w   = *p_tau_w;
    const float a       = *p_a;
    const float b       = *p_b;
    const float dt      = 5e-5f;

    const double dT  = (double)delta_T;
    const double dcv = (double)dt / (double)tau;
    const double dcw = (double)dt / (double)tau_w;
    const double l2e = 1.4426950408889634;

    const float c_exp = (float)(l2e / dT);
    const float c2    = (float)(log2(dT * dcv) - (double)V_T * (l2e / dT));
    const float alpha = (float)(1.0 - dcv);
    const float ncRv  = (float)(-dcv * (double)R);
    const float beta  = (float)(1.0 - dcw);
    const float gamma = (float)((double)a * dcw);
    const float delta = (float)(-(double)a * dcw * (double)V_rest);
    const float cRI   = (float)(dcv * (double)R);
    const float cVr2  = (float)(dcv * (double)V_rest);

    float V = V0[n];
    float w = w0[n];

    float* outVb = out + nbase;
    float* outWb = out + (size_t)T * N + nbase;

#define ADEX_STEP(Ar2_k)                                            \
    {                                                               \
        outVb[l] = V;                                               \
        outWb[l] = w;                                               \
        outVb += N;                                                 \
        outWb += N;                                                 \
        float u3 = fmaf(V, c_exp, c2);                              \
        float ex3;                                                  \
        asm("v_exp_f32 %0, %1" : "=v"(ex3) : "v"(u3));              \
        float m1  = fmaf(alpha, V, (Ar2_k));                        \
        float m2  = fmaf(ncRv, w, m1);                              \
        float Vn  = m2 + ex3;                                       \
        float t2  = fmaf(gamma, V, delta);                          \
        float wn  = fmaf(beta, w, t2);                              \
        bool  spike = V > V_thres;                                  \
        float wns = wn + b;                                         \
        Vn = spike ? V_reset : Vn;                                  \
        wn = spike ? wns : wn;                                      \
        V = Vn;                                                     \
        w = wn;                                                     \
    }

    float A[16], B[16];
#pragma unroll
    for (int j = 0; j < 16; ++j) A[j] = fmaf(cRI, I_ext[j], cVr2);

    for (int kb = 0; kb < T; kb += 32) {
#pragma unroll
        for (int j = 0; j < 16; ++j)
            B[j] = fmaf(cRI, I_ext[kb + 16 + j], cVr2);
#pragma unroll
        for (int j = 0; j < 16; ++j) ADEX_STEP(A[j]);
        {
            int pb = kb + 32;
            if (pb > T - 11) pb = T - 11;
#pragma unroll
            for (int j = 0; j < 16; ++j)
                A[j] = fmaf(cRI, I_ext[pb + j], cVr2);
        }
#pragma unroll
        for (int j = 0; j < 16; ++j) ADEX_STEP(B[j]);
    }
#undef ADEX_STEP
}

extern "C" void kernel_launch(void* const* d_in, const int* in_sizes, int n_in,
                              void* d_out, int out_size, void* d_ws, size_t ws_size,
                              hipStream_t stream) {
    const float* I_ext = (const float*)d_in[0];
    const float* V0    = (const float*)d_in[1];
    const float* w0    = (const float*)d_in[2];

    const int N = in_sizes[1];          // 1024 (multiple of 64)
    const int T = out_size / (2 * N);   // 40000 (multiple of 64)

    const size_t ws_need = (size_t)(T + 32) * sizeof(float2);

    if ((N % 64 == 0) && (T % 64 == 0) && d_ws != nullptr && ws_size >= ws_need) {
        adex_prep_kernel<<<(T + 32 + 255) / 256, 256, 0, stream>>>(
            I_ext,
            (const float*)d_in[3],      // V_rest
            (const float*)d_in[8],      // R
            (const float*)d_in[9],      // tau
            (const float*)d_in[10],     // tau_w
            (const float*)d_in[11],     // a
            (float2*)d_ws, T);
        adex_pc_kernel<<<N / 64, 128, 0, stream>>>(
            V0, w0,
            (const float*)d_in[4],      // V_reset
            (const float*)d_in[5],      // V_T
            (const float*)d_in[6],      // V_thres
            (const float*)d_in[7],      // delta_T
            (const float*)d_in[8],      // R
            (const float*)d_in[9],      // tau
            (const float*)d_in[10],     // tau_w
            (const float*)d_in[11],     // a
            (const float*)d_in[12],     // b
            (const float*)d_ws,
            (float*)d_out, T, N);
    } else {
        adex_fallback_kernel<<<(N + 63) / 64, 64, 0, stream>>>(
            I_ext, V0, w0,
            (const float*)d_in[3], (const float*)d_in[4], (const float*)d_in[5],
            (const float*)d_in[6], (const float*)d_in[7], (const float*)d_in[8],
            (const float*)d_in[9], (const float*)d_in[10], (const float*)d_in[11],
            (const float*)d_in[12], (float*)d_out, T, N);
    }
}